// Round 1
// baseline (480.251 us; speedup 1.0000x reference)
//
#include <hip/hip_runtime.h>
#include <hip/hip_bf16.h>
#include <math.h>

#define NROWS 4096
#define HD 512
#define HEADS 8
#define HDD 64
#define SEQ 1024

// ---------------- quantum gate helpers ----------------
// state: sr[16], si[16] in registers; qubit q (0..3) -> bit mask M = 1<<(3-q)
// All loops fully unrolled with compile-time masks so arrays stay in VGPRs.

template<int M>
__device__ __forceinline__ void g_rx(float* sr, float* si, float c, float s) {
#pragma unroll
  for (int a = 0; a < 16; ++a) if (!(a & M)) {
    const int b = a | M;
    float ar = sr[a], ai = si[a], br = sr[b], bi = si[b];
    sr[a] = c*ar + s*bi;  si[a] = c*ai - s*br;
    sr[b] = c*br + s*ai;  si[b] = c*bi - s*ar;
  }
}

template<int M>
__device__ __forceinline__ void g_ry(float* sr, float* si, float c, float s) {
#pragma unroll
  for (int a = 0; a < 16; ++a) if (!(a & M)) {
    const int b = a | M;
    float ar = sr[a], ai = si[a], br = sr[b], bi = si[b];
    sr[a] = c*ar - s*br;  si[a] = c*ai - s*bi;
    sr[b] = s*ar + c*br;  si[b] = s*ai + c*bi;
  }
}

template<int M>
__device__ __forceinline__ void g_rz(float* sr, float* si, float c, float s) {
#pragma unroll
  for (int a = 0; a < 16; ++a) if (!(a & M)) {
    const int b = a | M;
    float ar = sr[a], ai = si[a];
    sr[a] = c*ar + s*ai;  si[a] = c*ai - s*ar;       // * (c - i s)
    float br = sr[b], bi = si[b];
    sr[b] = c*br - s*bi;  si[b] = c*bi + s*br;       // * (c + i s)
  }
}

template<int M>
__device__ __forceinline__ void g_h(float* sr, float* si) {
  const float r2 = 0.70710678118654752440f;
#pragma unroll
  for (int a = 0; a < 16; ++a) if (!(a & M)) {
    const int b = a | M;
    float ar = sr[a], ai = si[a], br = sr[b], bi = si[b];
    sr[a] = (ar + br) * r2;  si[a] = (ai + bi) * r2;
    sr[b] = (ar - br) * r2;  si[b] = (ai - bi) * r2;
  }
}

template<int M>
__device__ __forceinline__ void g_x(float* sr, float* si) {
#pragma unroll
  for (int a = 0; a < 16; ++a) if (!(a & M)) {
    const int b = a | M;
    float t;
    t = sr[a]; sr[a] = sr[b]; sr[b] = t;
    t = si[a]; si[a] = si[b]; si[b] = t;
  }
}

template<int MC, int MT>
__device__ __forceinline__ void g_crx(float* sr, float* si, float c, float s) {
#pragma unroll
  for (int a = 0; a < 16; ++a) if ((a & MC) && !(a & MT)) {
    const int b = a | MT;
    float ar = sr[a], ai = si[a], br = sr[b], bi = si[b];
    sr[a] = c*ar + s*bi;  si[a] = c*ai - s*br;
    sr[b] = c*br + s*ai;  si[b] = c*bi - s*ar;
  }
}

template<int MC, int MT>
__device__ __forceinline__ void g_cnot(float* sr, float* si) {
#pragma unroll
  for (int a = 0; a < 16; ++a) if ((a & MC) && !(a & MT)) {
    const int b = a | MT;
    float t;
    t = sr[a]; sr[a] = sr[b]; sr[b] = t;
    t = si[a]; si[a] = si[b]; si[b] = t;
  }
}

template<int M>
__device__ __forceinline__ float expZ(const float* pr) {
  float z = 0.f;
#pragma unroll
  for (int a = 0; a < 16; ++a) z += (a & M) ? -pr[a] : pr[a];
  return z;
}

template<int M>
__device__ __forceinline__ float expX(const float* sr, const float* si) {
  float x = 0.f;
#pragma unroll
  for (int a = 0; a < 16; ++a) if (!(a & M)) {
    const int b = a | M;
    x += sr[a]*sr[b] + si[a]*si[b];
  }
  return 2.f * x;
}

template<int M>
__device__ __forceinline__ float expY(const float* sr, const float* si) {
  float y = 0.f;
#pragma unroll
  for (int a = 0; a < 16; ++a) if (!(a & M)) {
    const int b = a | M;
    y += sr[a]*si[b] - si[a]*sr[b];
  }
  return 2.f * y;
}

// ---------------- K1: p = LN(tanh(x @ Wp^T + bp)) ----------------
__global__ __launch_bounds__(256) void k_proj_ln(const float* __restrict__ x,
    const float* __restrict__ Wp, const float* __restrict__ bp,
    const float* __restrict__ g, const float* __restrict__ b,
    float* __restrict__ p) {
  int row  = blockIdx.x * 4 + (threadIdx.x >> 6);
  int lane = threadIdx.x & 63;
  const float* xr = x + row * HD + lane * 8;
  float4 xa = *(const float4*)xr;
  float4 xb = *(const float4*)(xr + 4);
  float acc[4];
#pragma unroll
  for (int j = 0; j < 4; ++j) {
    const float* wr = Wp + j * HD + lane * 8;
    float4 wa = *(const float4*)wr;
    float4 wb = *(const float4*)(wr + 4);
    acc[j] = xa.x*wa.x + xa.y*wa.y + xa.z*wa.z + xa.w*wa.w
           + xb.x*wb.x + xb.y*wb.y + xb.z*wb.z + xb.w*wb.w;
  }
#pragma unroll
  for (int j = 0; j < 4; ++j) {
#pragma unroll
    for (int off = 32; off >= 1; off >>= 1)
      acc[j] += __shfl_xor(acc[j], off);
  }
  if (lane == 0) {
    float v0 = tanhf(acc[0] + bp[0]);
    float v1 = tanhf(acc[1] + bp[1]);
    float v2 = tanhf(acc[2] + bp[2]);
    float v3 = tanhf(acc[3] + bp[3]);
    float mu = 0.25f * (v0 + v1 + v2 + v3);
    float d0 = v0 - mu, d1 = v1 - mu, d2 = v2 - mu, d3 = v3 - mu;
    float inv = rsqrtf(0.25f * (d0*d0 + d1*d1 + d2*d2 + d3*d3) + 1e-5f);
    *(float4*)(p + row * 4) = make_float4(d0*inv*g[0] + b[0], d1*inv*g[1] + b[1],
                                          d2*inv*g[2] + b[2], d3*inv*g[3] + b[3]);
  }
}

// ---------------- K2: quantum circuits -> t[3][4096][12] ----------------
__global__ __launch_bounds__(256) void k_circuits(const float* __restrict__ p,
    const float* __restrict__ w0, const float* __restrict__ e0,
    const float* __restrict__ g0, const float* __restrict__ b0,
    const float* __restrict__ w1, const float* __restrict__ e1,
    const float* __restrict__ g1, const float* __restrict__ b1,
    const float* __restrict__ w2, const float* __restrict__ e2,
    const float* __restrict__ g2, const float* __restrict__ b2,
    float* __restrict__ t) {
  int gid  = blockIdx.x * 256 + threadIdx.x;
  int circ = gid >> 12;          // /4096  (grid exactly 3*4096 threads)
  int row  = gid & (NROWS - 1);
  const float* w  = (circ == 0) ? w0 : ((circ == 1) ? w1 : w2);
  const float* ew = (circ == 0) ? e0 : ((circ == 1) ? e1 : e2);
  const float* gm = (circ == 0) ? g0 : ((circ == 1) ? g1 : g2);
  const float* bt = (circ == 0) ? b0 : ((circ == 1) ? b1 : b2);

  float sr[16], si[16];
#pragma unroll
  for (int a = 0; a < 16; ++a) { sr[a] = 0.f; si[a] = 0.f; }
  sr[0] = 1.f;

  float c, s;
  // AngleEmbedding: RY(inp[i]) on qubit i
  float4 in4 = *(const float4*)(p + row * 4);
  sincosf(0.5f * in4.x, &s, &c); g_ry<8>(sr, si, c, s);
  sincosf(0.5f * in4.y, &s, &c); g_ry<4>(sr, si, c, s);
  sincosf(0.5f * in4.z, &s, &c); g_ry<2>(sr, si, c, s);
  sincosf(0.5f * in4.w, &s, &c); g_ry<1>(sr, si, c, s);

  for (int L = 0; L < 3; ++L) {
    // RX,RY,RZ with the same angle per qubit
    sincosf(0.5f * w[L*4+0], &s, &c); g_rx<8>(sr,si,c,s); g_ry<8>(sr,si,c,s); g_rz<8>(sr,si,c,s);
    sincosf(0.5f * w[L*4+1], &s, &c); g_rx<4>(sr,si,c,s); g_ry<4>(sr,si,c,s); g_rz<4>(sr,si,c,s);
    sincosf(0.5f * w[L*4+2], &s, &c); g_rx<2>(sr,si,c,s); g_ry<2>(sr,si,c,s); g_rz<2>(sr,si,c,s);
    sincosf(0.5f * w[L*4+3], &s, &c); g_rx<1>(sr,si,c,s); g_ry<1>(sr,si,c,s); g_rz<1>(sr,si,c,s);
    // CRX entangling ring: ctrl i, tgt (i+1)%4
    sincosf(0.5f * ew[L*4+0], &s, &c); g_crx<8,4>(sr,si,c,s);
    sincosf(0.5f * ew[L*4+1], &s, &c); g_crx<4,2>(sr,si,c,s);
    sincosf(0.5f * ew[L*4+2], &s, &c); g_crx<2,1>(sr,si,c,s);
    sincosf(0.5f * ew[L*4+3], &s, &c); g_crx<1,8>(sr,si,c,s);
    // Grover diffusion
    g_h<8>(sr,si); g_h<4>(sr,si); g_h<2>(sr,si); g_h<1>(sr,si);
    g_x<8>(sr,si); g_x<4>(sr,si); g_x<2>(sr,si); g_x<1>(sr,si);
    g_h<1>(sr,si);
    { float tmp;  // CCCX: swap amplitudes 14 <-> 15
      tmp = sr[14]; sr[14] = sr[15]; sr[15] = tmp;
      tmp = si[14]; si[14] = si[15]; si[15] = tmp; }
    g_h<1>(sr,si);
    g_x<8>(sr,si); g_x<4>(sr,si); g_x<2>(sr,si); g_x<1>(sr,si);
    g_h<8>(sr,si); g_h<4>(sr,si); g_h<2>(sr,si); g_h<1>(sr,si);
    // QAOA cost: CNOT(i,i+1); RZ(gam) on i+1; CNOT(i,i+1)
    sincosf(0.5f * gm[L], &s, &c);
    g_cnot<8,4>(sr,si); g_rz<4>(sr,si,c,s); g_cnot<8,4>(sr,si);
    g_cnot<4,2>(sr,si); g_rz<2>(sr,si,c,s); g_cnot<4,2>(sr,si);
    g_cnot<2,1>(sr,si); g_rz<1>(sr,si,c,s); g_cnot<2,1>(sr,si);
    // mixer RX(bet) on all qubits
    sincosf(0.5f * bt[L], &s, &c);
    g_rx<8>(sr,si,c,s); g_rx<4>(sr,si,c,s); g_rx<2>(sr,si,c,s); g_rx<1>(sr,si,c,s);
  }

  float pr[16];
#pragma unroll
  for (int a = 0; a < 16; ++a) pr[a] = sr[a]*sr[a] + si[a]*si[a];
  float* to = t + (circ * NROWS + row) * 12;
  to[0]  = expZ<8>(pr);       to[1]  = expZ<4>(pr);
  to[2]  = expZ<2>(pr);       to[3]  = expZ<1>(pr);
  to[4]  = expX<8>(sr, si);   to[5]  = expX<4>(sr, si);
  to[6]  = expX<2>(sr, si);   to[7]  = expX<1>(sr, si);
  to[8]  = expY<8>(sr, si);   to[9]  = expY<4>(sr, si);
  to[10] = expY<2>(sr, si);   to[11] = expY<1>(sr, si);
}

// ---------------- K3: q/k/v = t @ W^T + b, written as (B,H,S,hd) ----------------
__global__ __launch_bounds__(256) void k_qkvproj(const float* __restrict__ t,
    const float* __restrict__ Wq, const float* __restrict__ bq,
    const float* __restrict__ Wk, const float* __restrict__ bk,
    const float* __restrict__ Wv, const float* __restrict__ bv,
    float* __restrict__ Qo, float* __restrict__ Ko, float* __restrict__ Vo) {
  int n = blockIdx.x;
  int tid = threadIdx.x;
  __shared__ float tt[3][12];
  if (tid < 36) {
    int cc = tid / 12, j = tid - cc * 12;
    tt[cc][j] = t[(cc * NROWS + n) * 12 + j];
  }
  __syncthreads();
  int bb = n >> 10, ss = n & 1023;
  for (int o = tid; o < HD; o += 256) {
    int h = o >> 6, d = o & 63;
    int oidx = ((bb * HEADS + h) * SEQ + ss) * HDD + d;
    float aq = bq[o], ak = bk[o], av = bv[o];
#pragma unroll
    for (int j = 0; j < 12; ++j) {
      aq += tt[0][j] * Wq[o * 12 + j];
      ak += tt[1][j] * Wk[o * 12 + j];
      av += tt[2][j] * Wv[o * 12 + j];
    }
    Qo[oidx] = aq; Ko[oidx] = ak; Vo[oidx] = av;
  }
}

// ---------------- K4: flash-style attention (fp32) ----------------
// grid (64 qtiles, 32 bh); block 256 = 4 waves; wave owns 4 q-rows; K/V chunks of 64 in LDS.
__global__ __launch_bounds__(256) void k_attn(const float* __restrict__ Q,
    const float* __restrict__ K, const float* __restrict__ V,
    float* __restrict__ O) {
  const int bh  = blockIdx.y;
  const int qt  = blockIdx.x;
  const int tid = threadIdx.x;
  const int wid = tid >> 6;
  const int lane = tid & 63;

  __shared__ float Ql[16][64];
  __shared__ float Kt[64][65];
  __shared__ float Vt[64][65];
  __shared__ float Pl[4][4][64];

  const float* Qb = Q + (bh * SEQ + qt * 16) * HDD;
  const float* Kb = K + bh * SEQ * HDD;
  const float* Vb = V + bh * SEQ * HDD;

  { // load Q tile: 16x64 floats
    int e = tid * 4;
    *(float4*)&Ql[e >> 6][e & 63] = *(const float4*)(Qb + e);
  }

  float m0 = -INFINITY, m1 = -INFINITY, m2 = -INFINITY, m3 = -INFINITY;
  float l0 = 0.f, l1 = 0.f, l2 = 0.f, l3 = 0.f;
  float a0 = 0.f, a1 = 0.f, a2 = 0.f, a3 = 0.f;

  for (int ch = 0; ch < SEQ / 64; ++ch) {
    __syncthreads();           // previous chunk fully consumed (and Ql ready at ch=0)
#pragma unroll
    for (int i = 0; i < 4; ++i) {         // stage 64x64 K and V
      int f = tid + i * 256;              // float4 index 0..1023
      int r = f >> 4;
      int cc = (f & 15) * 4;
      float4 kv = *(const float4*)(Kb + ch * 4096 + f * 4);
      float4 vv = *(const float4*)(Vb + ch * 4096 + f * 4);
      Kt[r][cc] = kv.x; Kt[r][cc+1] = kv.y; Kt[r][cc+2] = kv.z; Kt[r][cc+3] = kv.w;
      Vt[r][cc] = vv.x; Vt[r][cc+1] = vv.y; Vt[r][cc+2] = vv.z; Vt[r][cc+3] = vv.w;
    }
    __syncthreads();

    // scores: lane = key index within chunk
    float s0 = 0.f, s1 = 0.f, s2 = 0.f, s3 = 0.f;
#pragma unroll
    for (int d = 0; d < 64; d += 4) {
      float k0 = Kt[lane][d], k1 = Kt[lane][d+1], k2 = Kt[lane][d+2], k3 = Kt[lane][d+3];
      float4 q0 = *(const float4*)&Ql[wid*4+0][d];
      float4 q1 = *(const float4*)&Ql[wid*4+1][d];
      float4 q2 = *(const float4*)&Ql[wid*4+2][d];
      float4 q3 = *(const float4*)&Ql[wid*4+3][d];
      s0 += q0.x*k0 + q0.y*k1 + q0.z*k2 + q0.w*k3;
      s1 += q1.x*k0 + q1.y*k1 + q1.z*k2 + q1.w*k3;
      s2 += q2.x*k0 + q2.y*k1 + q2.z*k2 + q2.w*k3;
      s3 += q3.x*k0 + q3.y*k1 + q3.z*k2 + q3.w*k3;
    }

#define SOFTMAX_STEP(sv, mm, ll, aa, rr) { \
      float sx = sv * 0.125f; \
      float mx = sx; \
      mx = fmaxf(mx, __shfl_xor(mx, 32)); mx = fmaxf(mx, __shfl_xor(mx, 16)); \
      mx = fmaxf(mx, __shfl_xor(mx, 8));  mx = fmaxf(mx, __shfl_xor(mx, 4));  \
      mx = fmaxf(mx, __shfl_xor(mx, 2));  mx = fmaxf(mx, __shfl_xor(mx, 1));  \
      float mnew = fmaxf(mm, mx); \
      float pp = __expf(sx - mnew); \
      float ps = pp; \
      ps += __shfl_xor(ps, 32); ps += __shfl_xor(ps, 16); ps += __shfl_xor(ps, 8); \
      ps += __shfl_xor(ps, 4);  ps += __shfl_xor(ps, 2);  ps += __shfl_xor(ps, 1); \
      float corr = __expf(mm - mnew); \
      ll = ll * corr + ps; \
      aa *= corr; \
      mm = mnew; \
      Pl[wid][rr][lane] = pp; }

    SOFTMAX_STEP(s0, m0, l0, a0, 0)
    SOFTMAX_STEP(s1, m1, l1, a1, 1)
    SOFTMAX_STEP(s2, m2, l2, a2, 2)
    SOFTMAX_STEP(s3, m3, l3, a3, 3)
#undef SOFTMAX_STEP

    // PV: lane = output dim d
#pragma unroll
    for (int kk = 0; kk < 64; kk += 4) {
      float4 p0 = *(const float4*)&Pl[wid][0][kk];
      float4 p1 = *(const float4*)&Pl[wid][1][kk];
      float4 p2 = *(const float4*)&Pl[wid][2][kk];
      float4 p3 = *(const float4*)&Pl[wid][3][kk];
      float v0 = Vt[kk+0][lane], v1 = Vt[kk+1][lane], v2 = Vt[kk+2][lane], v3 = Vt[kk+3][lane];
      a0 += p0.x*v0 + p0.y*v1 + p0.z*v2 + p0.w*v3;
      a1 += p1.x*v0 + p1.y*v1 + p1.z*v2 + p1.w*v3;
      a2 += p2.x*v0 + p2.y*v1 + p2.z*v2 + p2.w*v3;
      a3 += p3.x*v0 + p3.y*v1 + p3.z*v2 + p3.w*v3;
    }
  }

  int bb = bh >> 3, h = bh & 7;
  int srow = qt * 16 + wid * 4;
  O[(bb * SEQ + srow + 0) * HD + h * 64 + lane] = a0 / l0;
  O[(bb * SEQ + srow + 1) * HD + h * 64 + lane] = a1 / l1;
  O[(bb * SEQ + srow + 2) * HD + h * 64 + lane] = a2 / l2;
  O[(bb * SEQ + srow + 3) * HD + h * 64 + lane] = a3 / l3;
}

// ---------------- K5: out = a @ Wo^T + bo ----------------
__global__ __launch_bounds__(256) void k_oproj(const float* __restrict__ a,
    const float* __restrict__ Wo, const float* __restrict__ bo,
    float* __restrict__ out) {
  int nb = blockIdx.x;            // 16 rows per block
  int tid = threadIdx.x;
  __shared__ float As[16][512];
#pragma unroll
  for (int i = 0; i < 8; ++i) {
    int f = tid + i * 256;        // float4 index 0..2047
    int e = f * 4;
    *(float4*)&As[e >> 9][e & 511] = *(const float4*)(a + nb * 16 * 512 + e);
  }
  __syncthreads();
  for (int oo = tid; oo < 512; oo += 256) {
    float acc[16];
#pragma unroll
    for (int r = 0; r < 16; ++r) acc[r] = 0.f;
    float bias = bo[oo];
    for (int cc = 0; cc < 512; cc += 4) {
      float4 wv = *(const float4*)(Wo + oo * 512 + cc);
#pragma unroll
      for (int r = 0; r < 16; ++r) {
        float4 av = *(const float4*)&As[r][cc];
        acc[r] += av.x*wv.x + av.y*wv.y + av.z*wv.z + av.w*wv.w;
      }
    }
#pragma unroll
    for (int r = 0; r < 16; ++r)
      out[(nb * 16 + r) * 512 + oo] = acc[r] + bias;
  }
}

// ---------------- launch ----------------
extern "C" void kernel_launch(void* const* d_in, const int* in_sizes, int n_in,
                              void* d_out, int out_size, void* d_ws, size_t ws_size,
                              hipStream_t stream) {
  const float* x    = (const float*)d_in[0];
  const float* Wp   = (const float*)d_in[1];
  const float* bp   = (const float*)d_in[2];
  const float* ln_g = (const float*)d_in[3];
  const float* ln_b = (const float*)d_in[4];
  const float* qw   = (const float*)d_in[5];
  const float* qe   = (const float*)d_in[6];
  const float* qg   = (const float*)d_in[7];
  const float* qb_  = (const float*)d_in[8];
  const float* kw   = (const float*)d_in[9];
  const float* ke   = (const float*)d_in[10];
  const float* kg   = (const float*)d_in[11];
  const float* kb_  = (const float*)d_in[12];
  const float* vw   = (const float*)d_in[13];
  const float* ve   = (const float*)d_in[14];
  const float* vg   = (const float*)d_in[15];
  const float* vb_  = (const float*)d_in[16];
  const float* Wq   = (const float*)d_in[17];
  const float* bq   = (const float*)d_in[18];
  const float* Wk   = (const float*)d_in[19];
  const float* bk   = (const float*)d_in[20];
  const float* Wv   = (const float*)d_in[21];
  const float* bv   = (const float*)d_in[22];
  const float* Wo   = (const float*)d_in[23];
  const float* bo   = (const float*)d_in[24];

  float* ws   = (float*)d_ws;
  float* pbuf = ws;                       // 4096*4            = 16384
  float* tbuf = ws + 16384;               // 3*4096*12         = 147456
  float* qbuf = ws + 163840;              // 4096*512          = 2097152
  float* kbuf = qbuf + NROWS * HD;
  float* vbuf = kbuf + NROWS * HD;
  float* abuf = vbuf + NROWS * HD;        // attention output (B,S,Hd)

  k_proj_ln<<<NROWS / 4, 256, 0, stream>>>(x, Wp, bp, ln_g, ln_b, pbuf);
  k_circuits<<<(3 * NROWS) / 256, 256, 0, stream>>>(pbuf,
      qw, qe, qg, qb_, kw, ke, kg, kb_, vw, ve, vg, vb_, tbuf);
  k_qkvproj<<<NROWS, 256, 0, stream>>>(tbuf, Wq, bq, Wk, bk, Wv, bv,
                                       qbuf, kbuf, vbuf);
  dim3 ga(SEQ / 16, 32);
  k_attn<<<ga, 256, 0, stream>>>(qbuf, kbuf, vbuf, abuf);
  k_oproj<<<NROWS / 16, 256, 0, stream>>>(abuf, Wo, bo, (float*)d_out);
}

// Round 2
// 109.091 us; speedup vs baseline: 4.4023x; 4.4023x over previous
//
#include <hip/hip_runtime.h>
#include <hip/hip_bf16.h>
#include <math.h>

#define NROWS 4096
#define HD 512
#define HEADS 8
#define HDD 64
#define SEQ 1024

typedef unsigned short u16;
typedef __attribute__((ext_vector_type(8))) short sh8;   // 8 bf16 (4 VGPRs)
typedef __attribute__((ext_vector_type(4))) float f4;    // MFMA accumulator

__device__ __forceinline__ f4 mfma16(sh8 a, sh8 b, f4 c) {
  return __builtin_amdgcn_mfma_f32_16x16x32_bf16(a, b, c, 0, 0, 0);
}

__device__ __forceinline__ u16 f2bf(float x) {
  union { float f; unsigned u; } v; v.f = x;
  unsigned r = v.u + 0x7fff + ((v.u >> 16) & 1);   // RNE
  return (u16)(r >> 16);
}

// XOR swizzle for [R][64]-bf16 (128B-row) LDS tiles: spreads the 16-lane
// same-column ds_read_b128 across 8 distinct 16B slots (16-way -> 2-way).
#define SWZ(r, cb) ((((r) * 128) + (cb)) ^ (((r) & 7) << 4))

// ---------------- quantum gate helpers (register statevector) ----------------
template<int M>
__device__ __forceinline__ void g_rx(float* sr, float* si, float c, float s) {
#pragma unroll
  for (int a = 0; a < 16; ++a) if (!(a & M)) {
    const int b = a | M;
    float ar = sr[a], ai = si[a], br = sr[b], bi = si[b];
    sr[a] = c*ar + s*bi;  si[a] = c*ai - s*br;
    sr[b] = c*br + s*ai;  si[b] = c*bi - s*ar;
  }
}

template<int M>
__device__ __forceinline__ void g_ry(float* sr, float* si, float c, float s) {
#pragma unroll
  for (int a = 0; a < 16; ++a) if (!(a & M)) {
    const int b = a | M;
    float ar = sr[a], ai = si[a], br = sr[b], bi = si[b];
    sr[a] = c*ar - s*br;  si[a] = c*ai - s*bi;
    sr[b] = s*ar + c*br;  si[b] = s*ai + c*bi;
  }
}

template<int M>
__device__ __forceinline__ void g_rz(float* sr, float* si, float c, float s) {
#pragma unroll
  for (int a = 0; a < 16; ++a) if (!(a & M)) {
    const int b = a | M;
    float ar = sr[a], ai = si[a];
    sr[a] = c*ar + s*ai;  si[a] = c*ai - s*ar;
    float br = sr[b], bi = si[b];
    sr[b] = c*br - s*bi;  si[b] = c*bi + s*br;
  }
}

template<int M>
__device__ __forceinline__ void g_h(float* sr, float* si) {
  const float r2 = 0.70710678118654752440f;
#pragma unroll
  for (int a = 0; a < 16; ++a) if (!(a & M)) {
    const int b = a | M;
    float ar = sr[a], ai = si[a], br = sr[b], bi = si[b];
    sr[a] = (ar + br) * r2;  si[a] = (ai + bi) * r2;
    sr[b] = (ar - br) * r2;  si[b] = (ai - bi) * r2;
  }
}

template<int M>
__device__ __forceinline__ void g_x(float* sr, float* si) {
#pragma unroll
  for (int a = 0; a < 16; ++a) if (!(a & M)) {
    const int b = a | M;
    float t;
    t = sr[a]; sr[a] = sr[b]; sr[b] = t;
    t = si[a]; si[a] = si[b]; si[b] = t;
  }
}

template<int MC, int MT>
__device__ __forceinline__ void g_crx(float* sr, float* si, float c, float s) {
#pragma unroll
  for (int a = 0; a < 16; ++a) if ((a & MC) && !(a & MT)) {
    const int b = a | MT;
    float ar = sr[a], ai = si[a], br = sr[b], bi = si[b];
    sr[a] = c*ar + s*bi;  si[a] = c*ai - s*br;
    sr[b] = c*br + s*ai;  si[b] = c*bi - s*ar;
  }
}

template<int MC, int MT>
__device__ __forceinline__ void g_cnot(float* sr, float* si) {
#pragma unroll
  for (int a = 0; a < 16; ++a) if ((a & MC) && !(a & MT)) {
    const int b = a | MT;
    float t;
    t = sr[a]; sr[a] = sr[b]; sr[b] = t;
    t = si[a]; si[a] = si[b]; si[b] = t;
  }
}

template<int M>
__device__ __forceinline__ float expZ(const float* pr) {
  float z = 0.f;
#pragma unroll
  for (int a = 0; a < 16; ++a) z += (a & M) ? -pr[a] : pr[a];
  return z;
}

template<int M>
__device__ __forceinline__ float expX(const float* sr, const float* si) {
  float x = 0.f;
#pragma unroll
  for (int a = 0; a < 16; ++a) if (!(a & M)) {
    const int b = a | M;
    x += sr[a]*sr[b] + si[a]*si[b];
  }
  return 2.f * x;
}

template<int M>
__device__ __forceinline__ float expY(const float* sr, const float* si) {
  float y = 0.f;
#pragma unroll
  for (int a = 0; a < 16; ++a) if (!(a & M)) {
    const int b = a | M;
    y += sr[a]*si[b] - si[a]*sr[b];
  }
  return 2.f * y;
}

// ---------------- K1: p = LN(tanh(x @ Wp^T + bp)) ----------------
__global__ __launch_bounds__(256) void k_proj_ln(const float* __restrict__ x,
    const float* __restrict__ Wp, const float* __restrict__ bp,
    const float* __restrict__ g, const float* __restrict__ b,
    float* __restrict__ p) {
  int row  = blockIdx.x * 4 + (threadIdx.x >> 6);
  int lane = threadIdx.x & 63;
  const float* xr = x + row * HD + lane * 8;
  float4 xa = *(const float4*)xr;
  float4 xb = *(const float4*)(xr + 4);
  float acc[4];
#pragma unroll
  for (int j = 0; j < 4; ++j) {
    const float* wr = Wp + j * HD + lane * 8;
    float4 wa = *(const float4*)wr;
    float4 wb = *(const float4*)(wr + 4);
    acc[j] = xa.x*wa.x + xa.y*wa.y + xa.z*wa.z + xa.w*wa.w
           + xb.x*wb.x + xb.y*wb.y + xb.z*wb.z + xb.w*wb.w;
  }
#pragma unroll
  for (int j = 0; j < 4; ++j) {
#pragma unroll
    for (int off = 32; off >= 1; off >>= 1)
      acc[j] += __shfl_xor(acc[j], off);
  }
  if (lane == 0) {
    float v0 = tanhf(acc[0] + bp[0]);
    float v1 = tanhf(acc[1] + bp[1]);
    float v2 = tanhf(acc[2] + bp[2]);
    float v3 = tanhf(acc[3] + bp[3]);
    float mu = 0.25f * (v0 + v1 + v2 + v3);
    float d0 = v0 - mu, d1 = v1 - mu, d2 = v2 - mu, d3 = v3 - mu;
    float inv = rsqrtf(0.25f * (d0*d0 + d1*d1 + d2*d2 + d3*d3) + 1e-5f);
    *(float4*)(p + row * 4) = make_float4(d0*inv*g[0] + b[0], d1*inv*g[1] + b[1],
                                          d2*inv*g[2] + b[2], d3*inv*g[3] + b[3]);
  }
}

// ---------------- K2: quantum circuits -> t[3][4096][12] ----------------
__global__ __launch_bounds__(256) void k_circuits(const float* __restrict__ p,
    const float* __restrict__ w0, const float* __restrict__ e0,
    const float* __restrict__ g0, const float* __restrict__ b0,
    const float* __restrict__ w1, const float* __restrict__ e1,
    const float* __restrict__ g1, const float* __restrict__ b1,
    const float* __restrict__ w2, const float* __restrict__ e2,
    const float* __restrict__ g2, const float* __restrict__ b2,
    float* __restrict__ t) {
  int gid  = blockIdx.x * 256 + threadIdx.x;
  int circ = gid >> 12;
  int row  = gid & (NROWS - 1);
  const float* w  = (circ == 0) ? w0 : ((circ == 1) ? w1 : w2);
  const float* ew = (circ == 0) ? e0 : ((circ == 1) ? e1 : e2);
  const float* gm = (circ == 0) ? g0 : ((circ == 1) ? g1 : g2);
  const float* bt = (circ == 0) ? b0 : ((circ == 1) ? b1 : b2);

  float sr[16], si[16];
#pragma unroll
  for (int a = 0; a < 16; ++a) { sr[a] = 0.f; si[a] = 0.f; }
  sr[0] = 1.f;

  float c, s;
  float4 in4 = *(const float4*)(p + row * 4);
  sincosf(0.5f * in4.x, &s, &c); g_ry<8>(sr, si, c, s);
  sincosf(0.5f * in4.y, &s, &c); g_ry<4>(sr, si, c, s);
  sincosf(0.5f * in4.z, &s, &c); g_ry<2>(sr, si, c, s);
  sincosf(0.5f * in4.w, &s, &c); g_ry<1>(sr, si, c, s);

  for (int L = 0; L < 3; ++L) {
    sincosf(0.5f * w[L*4+0], &s, &c); g_rx<8>(sr,si,c,s); g_ry<8>(sr,si,c,s); g_rz<8>(sr,si,c,s);
    sincosf(0.5f * w[L*4+1], &s, &c); g_rx<4>(sr,si,c,s); g_ry<4>(sr,si,c,s); g_rz<4>(sr,si,c,s);
    sincosf(0.5f * w[L*4+2], &s, &c); g_rx<2>(sr,si,c,s); g_ry<2>(sr,si,c,s); g_rz<2>(sr,si,c,s);
    sincosf(0.5f * w[L*4+3], &s, &c); g_rx<1>(sr,si,c,s); g_ry<1>(sr,si,c,s); g_rz<1>(sr,si,c,s);
    sincosf(0.5f * ew[L*4+0], &s, &c); g_crx<8,4>(sr,si,c,s);
    sincosf(0.5f * ew[L*4+1], &s, &c); g_crx<4,2>(sr,si,c,s);
    sincosf(0.5f * ew[L*4+2], &s, &c); g_crx<2,1>(sr,si,c,s);
    sincosf(0.5f * ew[L*4+3], &s, &c); g_crx<1,8>(sr,si,c,s);
    g_h<8>(sr,si); g_h<4>(sr,si); g_h<2>(sr,si); g_h<1>(sr,si);
    g_x<8>(sr,si); g_x<4>(sr,si); g_x<2>(sr,si); g_x<1>(sr,si);
    g_h<1>(sr,si);
    { float tmp;
      tmp = sr[14]; sr[14] = sr[15]; sr[15] = tmp;
      tmp = si[14]; si[14] = si[15]; si[15] = tmp; }
    g_h<1>(sr,si);
    g_x<8>(sr,si); g_x<4>(sr,si); g_x<2>(sr,si); g_x<1>(sr,si);
    g_h<8>(sr,si); g_h<4>(sr,si); g_h<2>(sr,si); g_h<1>(sr,si);
    sincosf(0.5f * gm[L], &s, &c);
    g_cnot<8,4>(sr,si); g_rz<4>(sr,si,c,s); g_cnot<8,4>(sr,si);
    g_cnot<4,2>(sr,si); g_rz<2>(sr,si,c,s); g_cnot<4,2>(sr,si);
    g_cnot<2,1>(sr,si); g_rz<1>(sr,si,c,s); g_cnot<2,1>(sr,si);
    sincosf(0.5f * bt[L], &s, &c);
    g_rx<8>(sr,si,c,s); g_rx<4>(sr,si,c,s); g_rx<2>(sr,si,c,s); g_rx<1>(sr,si,c,s);
  }

  float pr[16];
#pragma unroll
  for (int a = 0; a < 16; ++a) pr[a] = sr[a]*sr[a] + si[a]*si[a];
  float* to = t + (circ * NROWS + row) * 12;
  to[0]  = expZ<8>(pr);       to[1]  = expZ<4>(pr);
  to[2]  = expZ<2>(pr);       to[3]  = expZ<1>(pr);
  to[4]  = expX<8>(sr, si);   to[5]  = expX<4>(sr, si);
  to[6]  = expX<2>(sr, si);   to[7]  = expX<1>(sr, si);
  to[8]  = expY<8>(sr, si);   to[9]  = expY<4>(sr, si);
  to[10] = expY<2>(sr, si);   to[11] = expY<1>(sr, si);
}

// -------- K3: q/k/v = t @ W^T + b -> bf16; Q,K as [bh][s][64], V transposed [bh][64][s]
__global__ __launch_bounds__(256) void k_qkvproj(const float* __restrict__ t,
    const float* __restrict__ Wq, const float* __restrict__ bq,
    const float* __restrict__ Wk, const float* __restrict__ bk,
    const float* __restrict__ Wv, const float* __restrict__ bv,
    u16* __restrict__ Qo, u16* __restrict__ Ko, u16* __restrict__ Vto) {
  int n = blockIdx.x;
  int tid = threadIdx.x;
  __shared__ float tt[3][12];
  if (tid < 36) {
    int cc = tid / 12, j = tid - cc * 12;
    tt[cc][j] = t[(cc * NROWS + n) * 12 + j];
  }
  __syncthreads();
  int bb = n >> 10, ss = n & 1023;
  for (int o = tid; o < HD; o += 256) {
    int h = o >> 6, d = o & 63;
    float aq = bq[o], ak = bk[o], av = bv[o];
#pragma unroll
    for (int j = 0; j < 12; ++j) {
      aq += tt[0][j] * Wq[o * 12 + j];
      ak += tt[1][j] * Wk[o * 12 + j];
      av += tt[2][j] * Wv[o * 12 + j];
    }
    int bhh = bb * HEADS + h;
    Qo[(bhh * SEQ + ss) * HDD + d] = f2bf(aq);
    Ko[(bhh * SEQ + ss) * HDD + d] = f2bf(ak);
    Vto[(bhh * HDD + d) * SEQ + ss] = f2bf(av);
  }
}

// ---------------- K4: MFMA flash attention ----------------
// grid (16 qtiles, 32 bh); 4 waves; wave owns 16 q-rows; KV chunk 64.
__global__ __launch_bounds__(256) void k_attn_mfma(const u16* __restrict__ Q,
    const u16* __restrict__ K, const u16* __restrict__ Vt,
    u16* __restrict__ Ob) {
  const int bh = blockIdx.y, qt = blockIdx.x;
  const int tid = threadIdx.x, w = tid >> 6, l = tid & 63;
  const int lr = l & 15, lh = l >> 4;

  __shared__ u16 Kl[64 * 64];       // [key][d]   swizzled
  __shared__ u16 Vl[64 * 64];       // [d][key]   swizzled
  __shared__ u16 Pl[4][16 * 64];    // per-wave [q][key] swizzled

  const u16* Qb = Q + (bh * SEQ + qt * 64) * HDD;
  const u16* Kb = K + bh * SEQ * HDD;
  const u16* Vb = Vt + bh * HDD * SEQ;

  // Q A-fragments in registers: A[m=lr][k = kk*32 + lh*8 + b]
  sh8 qf[2];
#pragma unroll
  for (int kk = 0; kk < 2; ++kk)
    qf[kk] = *(const sh8*)(Qb + (w * 16 + lr) * HDD + kk * 32 + lh * 8);

  f4 oacc[4];
  float m[4], lsum[4];
#pragma unroll
  for (int n = 0; n < 4; ++n) oacc[n] = (f4){0.f, 0.f, 0.f, 0.f};
#pragma unroll
  for (int r = 0; r < 4; ++r) { m[r] = -1e30f; lsum[r] = 0.f; }

  for (int ch = 0; ch < SEQ / 64; ++ch) {
    __syncthreads();                       // prev chunk's K/V reads done
#pragma unroll
    for (int i = 0; i < 2; ++i) {
      int idx = i * 256 + tid;
      int r = idx >> 3, c8 = idx & 7;
      *(sh8*)((char*)Kl + SWZ(r, c8 * 16)) =
          *(const sh8*)(Kb + (ch * 64 + r) * HDD + c8 * 8);
      *(sh8*)((char*)Vl + SWZ(r, c8 * 16)) =
          *(const sh8*)(Vb + r * SEQ + ch * 64 + c8 * 8);
    }
    __syncthreads();

    // S = Q K^T : acc rows = q (lh*4+r), cols = key (n*16+lr)
    f4 sacc[4];
#pragma unroll
    for (int n = 0; n < 4; ++n) sacc[n] = (f4){0.f, 0.f, 0.f, 0.f};
#pragma unroll
    for (int kk = 0; kk < 2; ++kk) {
#pragma unroll
      for (int n = 0; n < 4; ++n) {
        sh8 kf = *(const sh8*)((const char*)Kl + SWZ(n * 16 + lr, kk * 64 + lh * 16));
        sacc[n] = mfma16(qf[kk], kf, sacc[n]);
      }
    }

    // online softmax (rows shared by the 16-lane group {same lh})
    float p[4][4];
#pragma unroll
    for (int n = 0; n < 4; ++n) sacc[n] *= 0.125f;
#pragma unroll
    for (int r = 0; r < 4; ++r) {
      float mx = fmaxf(fmaxf(sacc[0][r], sacc[1][r]), fmaxf(sacc[2][r], sacc[3][r]));
      mx = fmaxf(mx, __shfl_xor(mx, 1)); mx = fmaxf(mx, __shfl_xor(mx, 2));
      mx = fmaxf(mx, __shfl_xor(mx, 4)); mx = fmaxf(mx, __shfl_xor(mx, 8));
      float mnew = fmaxf(m[r], mx);
      float corr = __expf(m[r] - mnew);
      m[r] = mnew;
      float rs = 0.f;
#pragma unroll
      for (int n = 0; n < 4; ++n) { p[n][r] = __expf(sacc[n][r] - mnew); rs += p[n][r]; }
      rs += __shfl_xor(rs, 1); rs += __shfl_xor(rs, 2);
      rs += __shfl_xor(rs, 4); rs += __shfl_xor(rs, 8);
      lsum[r] = lsum[r] * corr + rs;
#pragma unroll
      for (int n = 0; n < 4; ++n) oacc[n][r] *= corr;
    }

    // P -> per-wave LDS (D-layout -> A-layout round trip)
#pragma unroll
    for (int r = 0; r < 4; ++r)
#pragma unroll
      for (int n = 0; n < 4; ++n)
        *(u16*)((char*)Pl[w] + SWZ(lh * 4 + r, (n * 16 + lr) * 2)) = f2bf(p[n][r]);
    __syncthreads();                       // cross-lane LDS ordering

    // O += P V : A[m=lr][k=key], B[k=key][n=d] from Vl[d][key]
#pragma unroll
    for (int kk = 0; kk < 2; ++kk) {
      sh8 pf = *(const sh8*)((const char*)Pl[w] + SWZ(lr, kk * 64 + lh * 16));
#pragma unroll
      for (int n = 0; n < 4; ++n) {
        sh8 vf = *(const sh8*)((const char*)Vl + SWZ(n * 16 + lr, kk * 64 + lh * 16));
        oacc[n] = mfma16(pf, vf, oacc[n]);
      }
    }
  }

  // write attention output as bf16 [B*S][512]
  int bb = bh >> 3, h = bh & 7;
#pragma unroll
  for (int r = 0; r < 4; ++r) {
    int row = qt * 64 + w * 16 + lh * 4 + r;
    float inv = 1.f / lsum[r];
#pragma unroll
    for (int n = 0; n < 4; ++n)
      Ob[(bb * SEQ + row) * HD + h * 64 + n * 16 + lr] = f2bf(oacc[n][r] * inv);
  }
}

// ---------------- K5: out = a @ Wo^T + bo (MFMA) ----------------
__global__ __launch_bounds__(256) void k_oproj_mfma(const u16* __restrict__ A,
    const u16* __restrict__ W, const float* __restrict__ bo,
    float* __restrict__ out) {
  const int nb = blockIdx.x, ob = blockIdx.y;
  const int tid = threadIdx.x, w = tid >> 6, l = tid & 63;
  const int lr = l & 15, lh = l >> 4;
  __shared__ u16 Al[64 * 64];
  __shared__ u16 Wl[64 * 64];
  f4 acc[4];
#pragma unroll
  for (int n = 0; n < 4; ++n) acc[n] = (f4){0.f, 0.f, 0.f, 0.f};
  for (int ch = 0; ch < 8; ++ch) {
    __syncthreads();
#pragma unroll
    for (int i = 0; i < 2; ++i) {
      int idx = i * 256 + tid;
      int r = idx >> 3, c8 = idx & 7;
      *(sh8*)((char*)Al + SWZ(r, c8 * 16)) =
          *(const sh8*)(A + (nb * 64 + r) * HD + ch * 64 + c8 * 8);
      *(sh8*)((char*)Wl + SWZ(r, c8 * 16)) =
          *(const sh8*)(W + (ob * 64 + r) * HD + ch * 64 + c8 * 8);
    }
    __syncthreads();
#pragma unroll
    for (int kk = 0; kk < 2; ++kk) {
      sh8 af = *(const sh8*)((const char*)Al + SWZ(w * 16 + lr, kk * 64 + lh * 16));
#pragma unroll
      for (int n = 0; n < 4; ++n) {
        sh8 wf = *(const sh8*)((const char*)Wl + SWZ(n * 16 + lr, kk * 64 + lh * 16));
        acc[n] = mfma16(af, wf, acc[n]);
      }
    }
  }
#pragma unroll
  for (int r = 0; r < 4; ++r) {
    int row = nb * 64 + w * 16 + lh * 4 + r;
#pragma unroll
    for (int n = 0; n < 4; ++n) {
      int col = ob * 64 + n * 16 + lr;
      out[row * HD + col] = acc[n][r] + bo[col];
    }
  }
}

// ---------------- K6: fp32 -> bf16 convert (Wo) ----------------
__global__ __launch_bounds__(256) void k_cvt(const float* __restrict__ in,
                                             u16* __restrict__ o, int n) {
  int i = (blockIdx.x * 256 + threadIdx.x) * 4;
  if (i < n) {
    float4 v = *(const float4*)(in + i);
    o[i]   = f2bf(v.x); o[i+1] = f2bf(v.y);
    o[i+2] = f2bf(v.z); o[i+3] = f2bf(v.w);
  }
}

// ---------------- launch ----------------
extern "C" void kernel_launch(void* const* d_in, const int* in_sizes, int n_in,
                              void* d_out, int out_size, void* d_ws, size_t ws_size,
                              hipStream_t stream) {
  const float* x    = (const float*)d_in[0];
  const float* Wp   = (const float*)d_in[1];
  const float* bp   = (const float*)d_in[2];
  const float* ln_g = (const float*)d_in[3];
  const float* ln_b = (const float*)d_in[4];
  const float* qw   = (const float*)d_in[5];
  const float* qe   = (const float*)d_in[6];
  const float* qg   = (const float*)d_in[7];
  const float* qb_  = (const float*)d_in[8];
  const float* kw   = (const float*)d_in[9];
  const float* ke   = (const float*)d_in[10];
  const float* kg   = (const float*)d_in[11];
  const float* kb_  = (const float*)d_in[12];
  const float* vw   = (const float*)d_in[13];
  const float* ve   = (const float*)d_in[14];
  const float* vg   = (const float*)d_in[15];
  const float* vb_  = (const float*)d_in[16];
  const float* Wq   = (const float*)d_in[17];
  const float* bq   = (const float*)d_in[18];
  const float* Wk   = (const float*)d_in[19];
  const float* bk   = (const float*)d_in[20];
  const float* Wv   = (const float*)d_in[21];
  const float* bv   = (const float*)d_in[22];
  const float* Wo   = (const float*)d_in[23];
  const float* bo   = (const float*)d_in[24];

  float* ws   = (float*)d_ws;
  float* pbuf = ws;                        // 16384 f
  float* tbuf = ws + 16384;                // 147456 f
  u16* qb  = (u16*)(tbuf + 147456);        // 32*1024*64
  u16* kb  = qb + 32 * SEQ * HDD;
  u16* vtb = kb + 32 * SEQ * HDD;
  u16* ab  = vtb + 32 * SEQ * HDD;         // 4096*512
  u16* wob = ab + NROWS * HD;              // 512*512

  k_proj_ln<<<NROWS / 4, 256, 0, stream>>>(x, Wp, bp, ln_g, ln_b, pbuf);
  k_circuits<<<(3 * NROWS) / 256, 256, 0, stream>>>(pbuf,
      qw, qe, qg, qb_, kw, ke, kg, kb_, vw, ve, vg, vb_, tbuf);
  k_qkvproj<<<NROWS, 256, 0, stream>>>(tbuf, Wq, bq, Wk, bk, Wv, bv,
                                       qb, kb, vtb);
  k_cvt<<<(HD * HD) / 1024, 256, 0, stream>>>(Wo, wob, HD * HD);
  dim3 ga(SEQ / 64, 32);
  k_attn_mfma<<<ga, 256, 0, stream>>>(qb, kb, vtb, ab);
  dim3 go(NROWS / 64, HD / 64);
  k_oproj_mfma<<<go, 256, 0, stream>>>(ab, wob, bo, (float*)d_out);
}